// Round 6
// baseline (587.741 us; speedup 1.0000x reference)
//
#include <hip/hip_runtime.h>

// Problem constants
constexpr int N_NODES = 50000;
constexpr int E_EDGES = 800000;
constexpr int CSR_CAP = E_EDGES + 4 * N_NODES;  // padded-to-4 capacity
constexpr int IN_DIM  = 128;
constexpr int HID     = 64;
constexpr int HEADS   = 4;
constexpr int HH      = HEADS * HID;            // 256
constexpr int EDGE_DIM = 8;
constexpr int L_LAYERS = 2;
constexpr float NEG_SLOPE = 0.2f;
constexpr int NB_ALLOC = (N_NODES + 255) / 256;  // 196

typedef float floatx2 __attribute__((ext_vector_type(2)));

__device__ __forceinline__ unsigned short f2bf(float f) {
    unsigned int b = __float_as_uint(f);
    unsigned int r = (b + 0x7FFFu + ((b >> 16) & 1u)) >> 16;  // RNE
    return (unsigned short)r;
}
__device__ __forceinline__ float bf2f(unsigned short u) {
    return __uint_as_float(((unsigned int)u) << 16);
}

// fp8 e4m3 (OCP) pack/unpack via gfx950 HW converts
__device__ __forceinline__ unsigned char f2fp8(float v) {
    return (unsigned char)(__builtin_amdgcn_cvt_pk_fp8_f32(v, v, 0, false) & 0xFF);
}

// ---------------- fused: proj (l0 input) + transform l0 --------------
__global__ void proj_transform0_kernel(const float* __restrict__ x, const float* __restrict__ w,
                                       const float* __restrict__ b, const float* __restrict__ Wl,
                                       const float* __restrict__ Wr, float* __restrict__ x0,
                                       unsigned char* __restrict__ xl, unsigned short* __restrict__ xr) {
    int base = blockIdx.x * 16;
    __shared__ float xs[16][IN_DIM];   // input tile
    __shared__ float xs2[16][HID];     // projected tile
    for (int i = threadIdx.x; i < 16 * IN_DIM; i += 256) {
        int r = i >> 7, k = i & 127;
        xs[r][k] = x[(size_t)(base + r) * IN_DIM + k];
    }
    __syncthreads();
    {
        int c = threadIdx.x & 63;
        int g = threadIdx.x >> 6;  // 0..3
        float acc[4];
        float bc = b[c];
#pragma unroll
        for (int j = 0; j < 4; ++j) acc[j] = bc;
        for (int k0 = 0; k0 < IN_DIM; k0 += 4) {
            float w0 = w[(k0 + 0) * HID + c];
            float w1 = w[(k0 + 1) * HID + c];
            float w2 = w[(k0 + 2) * HID + c];
            float w3 = w[(k0 + 3) * HID + c];
#pragma unroll
            for (int j = 0; j < 4; ++j) {
                float4 xv = *(const float4*)&xs[g + 4 * j][k0];
                acc[j] += xv.x * w0 + xv.y * w1 + xv.z * w2 + xv.w * w3;
            }
        }
#pragma unroll
        for (int j = 0; j < 4; ++j) {
            xs2[g + 4 * j][c] = acc[j];
            x0[(size_t)(base + g + 4 * j) * HID + c] = acc[j];
        }
    }
    __syncthreads();
    // transform phase: thread owns output column hc of HH=256
    int hc = threadIdx.x;
    float al[16], ar[16];
#pragma unroll
    for (int i = 0; i < 16; ++i) { al[i] = 0.f; ar[i] = 0.f; }
    for (int k0 = 0; k0 < HID; k0 += 4) {
        float wl0 = Wl[(k0 + 0) * HH + hc], wr0 = Wr[(k0 + 0) * HH + hc];
        float wl1 = Wl[(k0 + 1) * HH + hc], wr1 = Wr[(k0 + 1) * HH + hc];
        float wl2 = Wl[(k0 + 2) * HH + hc], wr2 = Wr[(k0 + 2) * HH + hc];
        float wl3 = Wl[(k0 + 3) * HH + hc], wr3 = Wr[(k0 + 3) * HH + hc];
#pragma unroll
        for (int i = 0; i < 16; ++i) {
            float4 xv = *(const float4*)&xs2[i][k0];
            al[i] += xv.x * wl0 + xv.y * wl1 + xv.z * wl2 + xv.w * wl3;
            ar[i] += xv.x * wr0 + xv.y * wr1 + xv.z * wr2 + xv.w * wr3;
        }
    }
#pragma unroll
    for (int i = 0; i < 16; ++i) {
        xl[(size_t)(base + i) * HH + hc] = f2fp8(al[i]);
        xr[(size_t)(base + i) * HH + hc] = f2bf(ar[i]);
    }
}

// ---------------- fused: deg histogram + edge-attr histogram ---------
__global__ void edge_stats_kernel(const int* __restrict__ dst, const int* __restrict__ attr,
                                  int* __restrict__ deg, int* __restrict__ counts) {
    int c0 = 0, c1 = 0, c2 = 0;
    for (int e = blockIdx.x * 256 + threadIdx.x; e < E_EDGES; e += gridDim.x * 256) {
        atomicAdd(&deg[dst[e]], 1);
        int a = attr[e];
        c0 += (a == 0); c1 += (a == 1); c2 += (a == 2);
    }
    for (int o = 32; o; o >>= 1) {
        c0 += __shfl_down(c0, o);
        c1 += __shfl_down(c1, o);
        c2 += __shfl_down(c2, o);
    }
    if ((threadIdx.x & 63) == 0) {
        atomicAdd(&counts[0], c0);
        atomicAdd(&counts[1], c1);
        atomicAdd(&counts[2], c2);
    }
}

// ---------------- alloc: cursor-based CSR segment allocation + eet ---
__global__ void alloc_kernel(const int* __restrict__ deg, int* __restrict__ cursor,
                             int* __restrict__ offsets, int* __restrict__ fill,
                             unsigned int* __restrict__ csr, const float* __restrict__ edge_emb,
                             const float* __restrict__ We, const int* __restrict__ counts,
                             float* __restrict__ eet) {
    if (blockIdx.x == NB_ALLOC) {
        // eet[l][t][hc] for both layers
        int hc = threadIdx.x;
        float inv = 1.f / (float)E_EDGES;
        for (int l = 0; l < L_LAYERS; ++l) {
            const float* We_l = We + (size_t)l * EDGE_DIM * HH;
            float* eet_l = eet + (size_t)l * 4 * HH;
            for (int t = 0; t < 3; ++t) {
                float acc = 0.f;
#pragma unroll
                for (int d = 0; d < EDGE_DIM; ++d) acc += edge_emb[t * EDGE_DIM + d] * We_l[d * HH + hc];
                eet_l[t * HH + hc] = acc;
            }
            float acc = 0.f;
#pragma unroll
            for (int d = 0; d < EDGE_DIM; ++d) {
                float md = (counts[0] * edge_emb[0 * EDGE_DIM + d] +
                            counts[1] * edge_emb[1 * EDGE_DIM + d] +
                            counts[2] * edge_emb[2 * EDGE_DIM + d]) * inv;
                acc += md * We_l[d * HH + hc];
            }
            eet_l[3 * HH + hc] = acc;
        }
        return;
    }
    int n = blockIdx.x * 256 + threadIdx.x;
    if (n >= N_NODES) return;
    int cnt = deg[n] + 1;
    int pad = (cnt + 3) & ~3;
    int off = atomicAdd(cursor, pad);
    offsets[n] = off;
    unsigned int selfe = (unsigned int)n | (3u << 16);  // type 3 = mean edge feat
    csr[off] = selfe;
    for (int p = cnt; p < pad; ++p) csr[off + p] = selfe;  // masked dummies
    fill[n] = off + 1;
}

__global__ void scatter_kernel(const int* __restrict__ src, const int* __restrict__ dst,
                               const int* __restrict__ attr, int* __restrict__ fill,
                               unsigned int* __restrict__ csr) {
    int e = blockIdx.x * 256 + threadIdx.x;
    if (e >= E_EDGES) return;
    int d = dst[e];
    int pos = atomicAdd(&fill[d], 1);
    csr[pos] = (unsigned int)src[e] | ((unsigned int)attr[e] << 16);
}

// ---------------- xl = x@Wl (fp8 out), xr = x@Wr (bf16 out) ----------
__global__ void transform_kernel(const float* __restrict__ x, const float* __restrict__ Wl,
                                 const float* __restrict__ Wr, unsigned char* __restrict__ xl,
                                 unsigned short* __restrict__ xr) {
    int base = blockIdx.x * 16;
    int hc = threadIdx.x;  // 256
    __shared__ float xs[16][HID];
    for (int i = threadIdx.x; i < 16 * HID; i += 256) {
        int r = i >> 6, k = i & 63;
        xs[r][k] = x[(size_t)(base + r) * HID + k];
    }
    __syncthreads();
    float al[16], ar[16];
#pragma unroll
    for (int i = 0; i < 16; ++i) { al[i] = 0.f; ar[i] = 0.f; }
    for (int k0 = 0; k0 < HID; k0 += 4) {
        float wl0 = Wl[(k0 + 0) * HH + hc], wr0 = Wr[(k0 + 0) * HH + hc];
        float wl1 = Wl[(k0 + 1) * HH + hc], wr1 = Wr[(k0 + 1) * HH + hc];
        float wl2 = Wl[(k0 + 2) * HH + hc], wr2 = Wr[(k0 + 2) * HH + hc];
        float wl3 = Wl[(k0 + 3) * HH + hc], wr3 = Wr[(k0 + 3) * HH + hc];
#pragma unroll
        for (int i = 0; i < 16; ++i) {
            float4 xv = *(const float4*)&xs[i][k0];
            al[i] += xv.x * wl0 + xv.y * wl1 + xv.z * wl2 + xv.w * wl3;
            ar[i] += xv.x * wr0 + xv.y * wr1 + xv.z * wr2 + xv.w * wr3;
        }
    }
#pragma unroll
    for (int i = 0; i < 16; ++i) {
        xl[(size_t)(base + i) * HH + hc] = f2fp8(al[i]);
        xr[(size_t)(base + i) * HH + hc] = f2bf(ar[i]);
    }
}

// ---------------- Fused GAT: score + softmax + aggregate + LN --------
// One wave per dst node; 4 edges/round; CSR+gathers prefetched one round
// ahead; packed-f32 (v_pk_*) score math.
__global__ __launch_bounds__(256, 8)
void gat_fused_kernel(const unsigned int* __restrict__ csr,
                      const int* __restrict__ offsets, const int* __restrict__ deg,
                      const unsigned char* __restrict__ xl,
                      const unsigned short* __restrict__ xr,
                      const float* __restrict__ eet_l, const float* __restrict__ att_l,
                      const float* __restrict__ bias_l, const float* __restrict__ lnw,
                      const float* __restrict__ lnb, const float* __restrict__ x_res,
                      float* __restrict__ x_out) {
    __shared__ float4 eetS[256];  // [4 types][64 lanes]
    eetS[threadIdx.x] = ((const float4*)eet_l)[threadIdx.x];
    __syncthreads();
    int n = blockIdx.x * 4 + (threadIdx.x >> 6);
    int lane = threadIdx.x & 63;
    float4 av = *(const float4*)(att_l + lane * 4);
    floatx2 av01 = {av.x, av.y}, av23 = {av.z, av.w};
    ushort4 xrv = *(const ushort4*)(xr + (size_t)n * HH + lane * 4);
    floatx2 xr01 = {bf2f(xrv.x), bf2f(xrv.y)};
    floatx2 xr23 = {bf2f(xrv.z), bf2f(xrv.w)};
    int beg = offsets[n];
    int cnt = deg[n] + 1;
    int rounds = (cnt + 3) >> 2;
    const unsigned char* xlb = xl + lane * 4;  // per-lane channel base (4 ch = 4 B)
    const unsigned int* cp = csr + beg;
    floatx2 accA01 = {0.f, 0.f}, accA23 = {0.f, 0.f};
    floatx2 accB01 = {0.f, 0.f}, accB23 = {0.f, 0.f};
    float denA = 0.f, denB = 0.f;

    auto gat_round = [&](uint4 ew, unsigned int xw0, unsigned int xw1, unsigned int xw2,
                         unsigned int xw3, int rem) {
        int t0 = ew.x >> 16, t1 = ew.y >> 16, t2 = ew.z >> 16, t3 = ew.w >> 16;
        float4 ee0 = eetS[(t0 << 6) + lane];
        float4 ee1 = eetS[(t1 << 6) + lane];
        float4 ee2 = eetS[(t2 << 6) + lane];
        float4 ee3 = eetS[(t3 << 6) + lane];
        floatx2 a01 = __builtin_amdgcn_cvt_pk_f32_fp8((int)xw0, false);
        floatx2 a23 = __builtin_amdgcn_cvt_pk_f32_fp8((int)xw0, true);
        floatx2 b01 = __builtin_amdgcn_cvt_pk_f32_fp8((int)xw1, false);
        floatx2 b23 = __builtin_amdgcn_cvt_pk_f32_fp8((int)xw1, true);
        floatx2 c01 = __builtin_amdgcn_cvt_pk_f32_fp8((int)xw2, false);
        floatx2 c23 = __builtin_amdgcn_cvt_pk_f32_fp8((int)xw2, true);
        floatx2 d01 = __builtin_amdgcn_cvt_pk_f32_fp8((int)xw3, false);
        floatx2 d23 = __builtin_amdgcn_cvt_pk_f32_fp8((int)xw3, true);
        floatx2 m;
        floatx2 l01, l23;
        m = a01 + xr01 + (floatx2){ee0.x, ee0.y};
        l01 = __builtin_elementwise_max(m, m * NEG_SLOPE);
        m = a23 + xr23 + (floatx2){ee0.z, ee0.w};
        l23 = __builtin_elementwise_max(m, m * NEG_SLOPE);
        floatx2 ps0 = l01 * av01 + l23 * av23;
        m = b01 + xr01 + (floatx2){ee1.x, ee1.y};
        l01 = __builtin_elementwise_max(m, m * NEG_SLOPE);
        m = b23 + xr23 + (floatx2){ee1.z, ee1.w};
        l23 = __builtin_elementwise_max(m, m * NEG_SLOPE);
        floatx2 ps1 = l01 * av01 + l23 * av23;
        m = c01 + xr01 + (floatx2){ee2.x, ee2.y};
        l01 = __builtin_elementwise_max(m, m * NEG_SLOPE);
        m = c23 + xr23 + (floatx2){ee2.z, ee2.w};
        l23 = __builtin_elementwise_max(m, m * NEG_SLOPE);
        floatx2 ps2 = l01 * av01 + l23 * av23;
        m = d01 + xr01 + (floatx2){ee3.x, ee3.y};
        l01 = __builtin_elementwise_max(m, m * NEG_SLOPE);
        m = d23 + xr23 + (floatx2){ee3.z, ee3.w};
        l23 = __builtin_elementwise_max(m, m * NEG_SLOPE);
        floatx2 ps3 = l01 * av01 + l23 * av23;
        float p0 = ps0.x + ps0.y, p1 = ps1.x + ps1.y;
        float p2 = ps2.x + ps2.y, p3 = ps3.x + ps3.y;
        p0 += __shfl_xor(p0, 1); p1 += __shfl_xor(p1, 1);
        p2 += __shfl_xor(p2, 1); p3 += __shfl_xor(p3, 1);
        p0 += __shfl_xor(p0, 2); p1 += __shfl_xor(p1, 2);
        p2 += __shfl_xor(p2, 2); p3 += __shfl_xor(p3, 2);
        p0 += __shfl_xor(p0, 4); p1 += __shfl_xor(p1, 4);
        p2 += __shfl_xor(p2, 4); p3 += __shfl_xor(p3, 4);
        p0 += __shfl_xor(p0, 8); p1 += __shfl_xor(p1, 8);
        p2 += __shfl_xor(p2, 8); p3 += __shfl_xor(p3, 8);
        float w0 = __expf(p0);
        float w1 = (rem > 1) ? __expf(p1) : 0.f;
        float w2 = (rem > 2) ? __expf(p2) : 0.f;
        float w3 = (rem > 3) ? __expf(p3) : 0.f;
        denA += w0 + w1;
        denB += w2 + w3;
        floatx2 wv;
        wv = {w0, w0}; accA01 += wv * a01; accA23 += wv * a23;
        wv = {w1, w1}; accA01 += wv * b01; accA23 += wv * b23;
        wv = {w2, w2}; accB01 += wv * c01; accB23 += wv * c23;
        wv = {w3, w3}; accB01 += wv * d01; accB23 += wv * d23;
    };

    uint4 ew = *(const uint4*)cp;
    unsigned int xw0 = *(const unsigned int*)(xlb + (size_t)(ew.x & 0xFFFFu) * HH);
    unsigned int xw1 = *(const unsigned int*)(xlb + (size_t)(ew.y & 0xFFFFu) * HH);
    unsigned int xw2 = *(const unsigned int*)(xlb + (size_t)(ew.z & 0xFFFFu) * HH);
    unsigned int xw3 = *(const unsigned int*)(xlb + (size_t)(ew.w & 0xFFFFu) * HH);
    for (int it = 1; it < rounds; ++it) {
        uint4 ewN = *(const uint4*)(cp + (it << 2));
        unsigned int yw0 = *(const unsigned int*)(xlb + (size_t)(ewN.x & 0xFFFFu) * HH);
        unsigned int yw1 = *(const unsigned int*)(xlb + (size_t)(ewN.y & 0xFFFFu) * HH);
        unsigned int yw2 = *(const unsigned int*)(xlb + (size_t)(ewN.z & 0xFFFFu) * HH);
        unsigned int yw3 = *(const unsigned int*)(xlb + (size_t)(ewN.w & 0xFFFFu) * HH);
        gat_round(ew, xw0, xw1, xw2, xw3, 4);  // all-but-last rounds are full
        ew = ewN; xw0 = yw0; xw1 = yw1; xw2 = yw2; xw3 = yw3;
    }
    gat_round(ew, xw0, xw1, xw2, xw3, cnt - ((rounds - 1) << 2));

    float inv = 1.f / (denA + denB);
    floatx2 r01 = (accA01 + accB01) * (floatx2){inv, inv};
    floatx2 r23 = (accA23 + accB23) * (floatx2){inv, inv};
    float r0 = r01.x, r1 = r01.y, r2 = r23.x, r3 = r23.y;
    // sum across heads (lanes differing in bits 4,5)
    r0 += __shfl_xor(r0, 16); r1 += __shfl_xor(r1, 16);
    r2 += __shfl_xor(r2, 16); r3 += __shfl_xor(r3, 16);
    r0 += __shfl_xor(r0, 32); r1 += __shfl_xor(r1, 32);
    r2 += __shfl_xor(r2, 32); r3 += __shfl_xor(r3, 32);
    if (lane < 16) {
        float4 xc = *(const float4*)(x_res + (size_t)n * HID + lane * 4);
        float4 bb = *(const float4*)(bias_l + lane * 4);
        float h0 = 0.25f * r0 + bb.x + xc.x;
        float h1 = 0.25f * r1 + bb.y + xc.y;
        float h2 = 0.25f * r2 + bb.z + xc.z;
        float h3 = 0.25f * r3 + bb.w + xc.w;
        float sum = h0 + h1 + h2 + h3;
        sum += __shfl_xor(sum, 1); sum += __shfl_xor(sum, 2);
        sum += __shfl_xor(sum, 4); sum += __shfl_xor(sum, 8);
        float mu = sum * (1.f / 64.f);
        float d0_ = h0 - mu, d1_ = h1 - mu, d2_ = h2 - mu, d3_ = h3 - mu;
        float vs = d0_ * d0_ + d1_ * d1_ + d2_ * d2_ + d3_ * d3_;
        vs += __shfl_xor(vs, 1); vs += __shfl_xor(vs, 2);
        vs += __shfl_xor(vs, 4); vs += __shfl_xor(vs, 8);
        float rstd = rsqrtf(vs * (1.f / 64.f) + 1e-5f);
        float4 w4 = *(const float4*)(lnw + lane * 4);
        float4 b4 = *(const float4*)(lnb + lane * 4);
        float4 o;
        o.x = d0_ * rstd * w4.x + b4.x;
        o.y = d1_ * rstd * w4.y + b4.y;
        o.z = d2_ * rstd * w4.z + b4.z;
        o.w = d3_ * rstd * w4.w + b4.w;
        *(float4*)(x_out + (size_t)n * HID + lane * 4) = o;
    }
}

extern "C" void kernel_launch(void* const* d_in, const int* in_sizes, int n_in,
                              void* d_out, int out_size, void* d_ws, size_t ws_size,
                              hipStream_t stream) {
    const float* x_in     = (const float*)d_in[0];
    const int*   edge_idx = (const int*)d_in[1];
    const int*   attr     = (const int*)d_in[2];
    const float* proj_w   = (const float*)d_in[3];
    const float* proj_b   = (const float*)d_in[4];
    const float* edge_emb = (const float*)d_in[5];
    const float* Wl       = (const float*)d_in[6];
    const float* Wr       = (const float*)d_in[7];
    const float* We       = (const float*)d_in[8];
    const float* att      = (const float*)d_in[9];
    const float* bias     = (const float*)d_in[10];
    const float* ln_w     = (const float*)d_in[11];
    const float* ln_b     = (const float*)d_in[12];
    float* out = (float*)d_out;

    const int* src_idx = edge_idx;
    const int* dst_idx = edge_idx + E_EDGES;

    // Workspace layout
    float* ws = (float*)d_ws;
    float* x0 = ws;                                            // N*HID f32
    float* x1 = x0 + (size_t)N_NODES * HID;                    // N*HID f32
    unsigned char* xl_f8 = (unsigned char*)(x1 + (size_t)N_NODES * HID);     // N*HH u8
    unsigned short* xr_bf = (unsigned short*)(xl_f8 + (size_t)N_NODES * HH); // N*HH u16
    unsigned int* csr = (unsigned int*)(xr_bf + (size_t)N_NODES * HH);       // CSR_CAP
    int* offsets = (int*)(csr + CSR_CAP);                      // N
    int* fill    = offsets + N_NODES;                          // N
    // zeroed region: deg[N], counts[4], cursor[1] (contiguous, one memset)
    int* deg     = fill + N_NODES;                             // N
    int* counts  = deg + N_NODES;                              // 4
    int* cursor  = counts + 4;                                 // 1
    float* eet   = (float*)(cursor + 1);                       // L*4*HH

    hipMemsetAsync(deg, 0, (size_t)(N_NODES + 5) * sizeof(int), stream);

    edge_stats_kernel<<<1024, 256, 0, stream>>>(dst_idx, attr, deg, counts);
    alloc_kernel<<<NB_ALLOC + 1, 256, 0, stream>>>(deg, cursor, offsets, fill, csr,
                                                   edge_emb, We, counts, eet);
    scatter_kernel<<<(E_EDGES + 255) / 256, 256, 0, stream>>>(src_idx, dst_idx, attr, fill, csr);
    proj_transform0_kernel<<<N_NODES / 16, 256, 0, stream>>>(x_in, proj_w, proj_b,
                                                             Wl, Wr, x0, xl_f8, xr_bf);
    gat_fused_kernel<<<N_NODES / 4, 256, 0, stream>>>(csr, offsets, deg, xl_f8, xr_bf, eet,
                                                      att, bias, ln_w, ln_b, x0, x1);
    transform_kernel<<<N_NODES / 16, 256, 0, stream>>>(x1, Wl + (size_t)HID * HH,
                                                       Wr + (size_t)HID * HH, xl_f8, xr_bf);
    gat_fused_kernel<<<N_NODES / 4, 256, 0, stream>>>(csr, offsets, deg, xl_f8, xr_bf,
                                                      eet + 4 * HH, att + HH, bias + HID,
                                                      ln_w + HID, ln_b + HID, x1, out);
}